// Round 6
// baseline (2247.097 us; speedup 1.0000x reference)
//
#include <hip/hip_runtime.h>

#define TT 512
#define HH 256
#define BB 128

typedef unsigned long long u64;

// 256 wgs x 1024 threads, cooperative, 1 wg/CU. Group g (= wg & 31) = wgs
// {g, g+32, ..., g+224} (same XCD under round-robin dispatch), batches
// 4g..4g+3. Member q = wg>>5 owns h elements [32q, 32q+32) (gate rows
// G*256 + 32q + [0,32) for G in {i,f,g,o}). Thread holds 2 rows x 16 K
// = 32 weight floats in VGPRs (fits the 64-VGPR budget of 1024-thr blocks).
//
// Exchange: epoch-tagged 8B payloads {epoch,h}, relaxed agent atomics.
// Import is WAVE-PRIVATE: wave s consumes only h[16s..16s+16) x 4 batches
// = 64 payloads = its 64 lanes. Each lane polls its payload, ds_writes it,
// one lgkmcnt(0) (wave64 lockstep => all 64 writes drained), then the wave
// enters its dot with no __syncthreads. No barrier after publish either:
// the next step's poll is the synchronization.
__global__ __launch_bounds__(1024)
__attribute__((amdgpu_waves_per_eu(4, 4)))
void lstm_coop(
    const float* __restrict__ x,      // [B,T]
    const float* __restrict__ W_ih,   // [1024]
    const float* __restrict__ W_hh,   // [1024,256]
    const float* __restrict__ b_ih,   // [1024]
    const float* __restrict__ b_hh,   // [1024]
    const float* __restrict__ W1,     // [128,256]
    const float* __restrict__ b1,     // [128]
    const float* __restrict__ W2,     // [128]
    const float* __restrict__ b2,     // [1]
    float* __restrict__ out,          // [B]
    u64* __restrict__ hpair)          // [2][BB][HH] {epoch,h}
{
    const int wg  = blockIdx.x;
    const int g   = wg & 31;          // group id
    const int q   = wg >> 5;          // member 0..7
    const int tid = threadIdx.x;
    const int b0  = 4 * g;

    __shared__ float x_lds[4][TT];           // 8 KB
    __shared__ float h_lds[4][HH];           // 4 KB
    __shared__ float part_lds[16][128][4];   // 32 KB
    __shared__ float pre_lds[128][4];        // 2 KB
    __shared__ float red_lds[4][128];        // 2 KB

    const int s    = tid >> 6;        // wave id = K-chunk of 16
    const int lane = tid & 63;
    const int r2   = lane;            // row pair: local rows r2 and r2+64
    const int lA = r2, lB = r2 + 64;
    const int RA = (lA >> 5) * HH + q * 32 + (lA & 31);
    const int RB = (lB >> 5) * HH + q * 32 + (lB & 31);

    // import mapping: lane -> (batch pm, element pj) of chunk s
    const int pm = lane >> 4;
    const int pj = 16 * s + (lane & 15);
    const u64* imp_base = &hpair[(size_t)(b0 + pm) * HH + pj];

    // resident weights: 2 rows x 16 K = 32 VGPRs
    float wA[16], wB[16];
    {
        const float4* pa = reinterpret_cast<const float4*>(W_hh + (size_t)RA * HH + 16 * s);
        const float4* pb = reinterpret_cast<const float4*>(W_hh + (size_t)RB * HH + 16 * s);
        #pragma unroll
        for (int k = 0; k < 4; ++k) {
            float4 va = pa[k], vb = pb[k];
            wA[4*k+0] = va.x; wA[4*k+1] = va.y; wA[4*k+2] = va.z; wA[4*k+3] = va.w;
            wB[4*k+0] = vb.x; wB[4*k+1] = vb.y; wB[4*k+2] = vb.z; wB[4*k+3] = vb.w;
        }
    }
    #pragma unroll
    for (int k = 0; k < 16; ++k) {
        asm volatile("" : "+v"(wA[k]));
        asm volatile("" : "+v"(wB[k]));
    }

    // reduce-phase constants: reduce thread (tid<512) covers row rr = tid>>2
    const int rr = (tid >> 2) & 127;
    const int RR = (rr >> 5) * HH + q * 32 + (rr & 31);
    const float wih_r  = W_ih[RR];
    const float bias_r = b_ih[RR] + b_hh[RR];

    // stage x for 4 batches (2048 elems, 2 per thread)
    #pragma unroll
    for (int u = 0; u < 2; ++u) {
        int idx = tid + u * 1024;
        int m = idx >> 9, j = idx & 511;
        x_lds[m][j] = x[(size_t)(b0 + m) * TT + j];
    }

    float c = 0.0f;                   // cell state for tid<128
    __syncthreads();

    for (int t = 0; t < TT; ++t) {
        // ---- wave-private import of chunk s (epoch t, slot t&1)
        {
            const u64* src = imp_base + (size_t)(t & 1) * BB * HH;
            u64 v = __hip_atomic_load(src, __ATOMIC_RELAXED, __HIP_MEMORY_SCOPE_AGENT);
            while ((unsigned)(v >> 32) < (unsigned)t) {
                __builtin_amdgcn_s_sleep(1);
                v = __hip_atomic_load(src, __ATOMIC_RELAXED, __HIP_MEMORY_SCOPE_AGENT);
            }
            h_lds[pm][pj] = __uint_as_float((unsigned)v);
        }
        // all 64 lanes' ds_writes drained before any lane's ds_read (lockstep wave)
        asm volatile("s_waitcnt lgkmcnt(0)" ::: "memory");
        __builtin_amdgcn_sched_barrier(0);

        // ---- dot: 2 rows x 16 K x 4 batches = 128 FMA from registers
        float accA[4], accB[4];
        #pragma unroll
        for (int m = 0; m < 4; ++m) {
            const float4* hm = reinterpret_cast<const float4*>(&h_lds[m][16 * s]);
            float4 h0 = hm[0], h1 = hm[1], h2 = hm[2], h3 = hm[3];
            float aa, ab;
            aa = wA[0] * h0.x;                     ab = wB[0] * h0.x;
            aa = __builtin_fmaf(wA[1],  h0.y, aa); ab = __builtin_fmaf(wB[1],  h0.y, ab);
            aa = __builtin_fmaf(wA[2],  h0.z, aa); ab = __builtin_fmaf(wB[2],  h0.z, ab);
            aa = __builtin_fmaf(wA[3],  h0.w, aa); ab = __builtin_fmaf(wB[3],  h0.w, ab);
            aa = __builtin_fmaf(wA[4],  h1.x, aa); ab = __builtin_fmaf(wB[4],  h1.x, ab);
            aa = __builtin_fmaf(wA[5],  h1.y, aa); ab = __builtin_fmaf(wB[5],  h1.y, ab);
            aa = __builtin_fmaf(wA[6],  h1.z, aa); ab = __builtin_fmaf(wB[6],  h1.z, ab);
            aa = __builtin_fmaf(wA[7],  h1.w, aa); ab = __builtin_fmaf(wB[7],  h1.w, ab);
            aa = __builtin_fmaf(wA[8],  h2.x, aa); ab = __builtin_fmaf(wB[8],  h2.x, ab);
            aa = __builtin_fmaf(wA[9],  h2.y, aa); ab = __builtin_fmaf(wB[9],  h2.y, ab);
            aa = __builtin_fmaf(wA[10], h2.z, aa); ab = __builtin_fmaf(wB[10], h2.z, ab);
            aa = __builtin_fmaf(wA[11], h2.w, aa); ab = __builtin_fmaf(wB[11], h2.w, ab);
            aa = __builtin_fmaf(wA[12], h3.x, aa); ab = __builtin_fmaf(wB[12], h3.x, ab);
            aa = __builtin_fmaf(wA[13], h3.y, aa); ab = __builtin_fmaf(wB[13], h3.y, ab);
            aa = __builtin_fmaf(wA[14], h3.z, aa); ab = __builtin_fmaf(wB[14], h3.z, ab);
            aa = __builtin_fmaf(wA[15], h3.w, aa); ab = __builtin_fmaf(wB[15], h3.w, ab);
            accA[m] = aa; accB[m] = ab;
        }
        *reinterpret_cast<float4*>(&part_lds[s][lA][0]) =
            make_float4(accA[0], accA[1], accA[2], accA[3]);
        *reinterpret_cast<float4*>(&part_lds[s][lB][0]) =
            make_float4(accB[0], accB[1], accB[2], accB[3]);
        __syncthreads();

        // ---- reduce over 16 K-chunks + input/bias: 512 threads (row rr, batch mm)
        if (tid < 512) {
            const int mm = tid & 3;
            float v = 0.f;
            #pragma unroll
            for (int ss = 0; ss < 16; ++ss) v += part_lds[ss][rr][mm];
            pre_lds[rr][mm] = v + __builtin_fmaf(x_lds[mm][t], wih_r, bias_r);
        }
        __syncthreads();

        // ---- cell update + publish: 128 threads (m = tid&3, l = tid>>2)
        if (tid < 128) {
            const int m = tid & 3;
            const int l = tid >> 2;
            float ig = pre_lds[l     ][m];
            float fg = pre_lds[32 + l][m];
            float gg = pre_lds[64 + l][m];
            float og = pre_lds[96 + l][m];
            ig = __builtin_amdgcn_rcpf(1.f + __expf(-ig));
            fg = __builtin_amdgcn_rcpf(1.f + __expf(-fg));
            og = __builtin_amdgcn_rcpf(1.f + __expf(-og));
            gg = 2.f * __builtin_amdgcn_rcpf(1.f + __expf(-2.f * gg)) - 1.f;
            c = __builtin_fmaf(fg, c, ig * gg);
            float th = 2.f * __builtin_amdgcn_rcpf(1.f + __expf(-2.f * c)) - 1.f;
            float hn = og * th;
            const int e = q * 32 + l;
            u64 pk = ((u64)(unsigned)(t + 1) << 32) | (u64)__float_as_uint(hn);
            __hip_atomic_store(&hpair[((size_t)((t + 1) & 1) * BB + (b0 + m)) * HH + e], pk,
                               __ATOMIC_RELAXED, __HIP_MEMORY_SCOPE_AGENT);
        }
        // no barrier: next step's poll is the synchronization
    }

    // ---- epilogue: wg q==0 imports final h (epoch TT, slot TT&1 = 0) and runs MLP
    if (q == 0) {
        {
            const u64* src = imp_base + (size_t)(TT & 1) * BB * HH;
            u64 v = __hip_atomic_load(src, __ATOMIC_RELAXED, __HIP_MEMORY_SCOPE_AGENT);
            while ((unsigned)(v >> 32) < (unsigned)TT) {
                __builtin_amdgcn_s_sleep(1);
                v = __hip_atomic_load(src, __ATOMIC_RELAXED, __HIP_MEMORY_SCOPE_AGENT);
            }
            h_lds[pm][pj] = __uint_as_float((unsigned)v);
        }
        __syncthreads();

        if (tid < 512) {
            const int m = tid >> 7, j = tid & 127;
            const float4* w1p = reinterpret_cast<const float4*>(W1 + (size_t)j * HH);
            const float4* hp  = reinterpret_cast<const float4*>(&h_lds[m][0]);
            float s0 = 0.f, s1 = 0.f, s2 = 0.f, s3 = 0.f;
            #pragma unroll
            for (int k = 0; k < 64; ++k) {
                float4 wv = w1p[k], hv = hp[k];
                s0 = __builtin_fmaf(wv.x, hv.x, s0);
                s1 = __builtin_fmaf(wv.y, hv.y, s1);
                s2 = __builtin_fmaf(wv.z, hv.z, s2);
                s3 = __builtin_fmaf(wv.w, hv.w, s3);
            }
            float rv = fmaxf((s0 + s1) + (s2 + s3) + b1[j], 0.f);
            red_lds[m][j] = rv * W2[j];
        }
        __syncthreads();
        if (tid < 4) {
            float y = b2[0];
            for (int k = 0; k < 128; ++k) y += red_lds[tid][k];
            out[b0 + tid] = y;
        }
    }
}

extern "C" void kernel_launch(void* const* d_in, const int* in_sizes, int n_in,
                              void* d_out, int out_size, void* d_ws, size_t ws_size,
                              hipStream_t stream) {
    const float* x    = (const float*)d_in[0];
    const float* W_ih = (const float*)d_in[1];
    const float* W_hh = (const float*)d_in[2];
    const float* b_ih = (const float*)d_in[3];
    const float* b_hh = (const float*)d_in[4];
    const float* W1   = (const float*)d_in[5];
    const float* b1   = (const float*)d_in[6];
    const float* W2   = (const float*)d_in[7];
    const float* b2   = (const float*)d_in[8];
    float* out  = (float*)d_out;

    u64* hpair = (u64*)d_ws;                    // [2][128][256] x 8B = 512 KB

    // epochs must be 0 at every call (d_ws keeps state across graph replays)
    hipMemsetAsync(d_ws, 0, (size_t)2 * BB * HH * sizeof(u64), stream);

    void* args[] = {(void*)&x, (void*)&W_ih, (void*)&W_hh, (void*)&b_ih, (void*)&b_hh,
                    (void*)&W1, (void*)&b1, (void*)&W2, (void*)&b2,
                    (void*)&out, (void*)&hpair};
    hipLaunchCooperativeKernel((void*)lstm_coop, dim3(256), dim3(1024), args, 0, stream);
}